// Round 2
// baseline (1950.572 us; speedup 1.0000x reference)
//
#include <hip/hip_runtime.h>
#include <hip/hip_bf16.h>

// MDN: B=65536, COND=32, D=16, H=256, K=16
//  pi    = softmax(z @ Wpi + bpi)            [B,16]
//  sigma = diag_embed(exp(z @ Wsig + bsig))  [B,16,16,16]
//  mu    = z @ Wmu + bmu                     [B,16,16]
//  z = tanh(x @ W1 + b1)                     [B,256]
//
// Write-bound: 1.145 GB of output => ~176 us floor at 6.5 TB/s.
// R1 change: no LDS weight staging -> ZERO barriers after the z-phase, so
// stores stream continuously (R0's per-chunk __syncthreads drained vmcnt(0)
// 8x per block and capped us at 2.8 TB/s). Weights read per-fragment from
// global (L2-resident, shared by all blocks). Nontemporal sigma/mu stores.

typedef __attribute__((ext_vector_type(8))) short short8;   // 8 bf16
typedef __attribute__((ext_vector_type(4))) float f32x4;

#define NB 65536
#define TB 64          // batch rows per block
#define HID 256
#define CIN 32

// ws layout (bf16): wpi_t [16][256] | wsig_t [256][256] | wmu_t [256][256]
#define WPI_OFF  0
#define WSIG_OFF (16*256)
#define WMU_OFF  (16*256 + 256*256)

__global__ __launch_bounds__(256) void cvt_weights(
    const float* __restrict__ Wpi, const float* __restrict__ Wsig,
    const float* __restrict__ Wmu, __hip_bfloat16* __restrict__ wsb)
{
    int r = blockIdx.x;      // 0..527 = output col -> transposed row
    int k = threadIdx.x;     // 0..255 = H index
    if (r < 16)
        wsb[WPI_OFF + r*256 + k] = __float2bfloat16(Wpi[k*16 + r]);
    else if (r < 272)
        wsb[WSIG_OFF + (r-16)*256 + k] = __float2bfloat16(Wsig[k*256 + (r-16)]);
    else
        wsb[WMU_OFF + (r-272)*256 + k] = __float2bfloat16(Wmu[k*256 + (r-272)]);
}

__global__ __launch_bounds__(256, 3) void mdn_main(
    const float* __restrict__ x, const float* __restrict__ W1,
    const float* __restrict__ b1, const float* __restrict__ bpi,
    const float* __restrict__ bsig, const float* __restrict__ bmu,
    const __hip_bfloat16* __restrict__ wsb,
    float* __restrict__ out)
{
    // LDS: x tile 8KB + z tile 33KB = 41KB -> 3 blocks/CU
    __shared__ alignas(16) float xs[TB*CIN];
    __shared__ alignas(16) __hip_bfloat16 zs[TB][264];   // 264 = 33 short8/row

    const int t  = threadIdx.x;
    const int b0 = blockIdx.x * TB;

    float* out_pi  = out;
    float* out_sig = out + (size_t)NB*16;
    float* out_mu  = out + (size_t)NB*16 + (size_t)NB*4096;

    // ---- load x tile [64][32] (coalesced float4) ----
    {
        const float4* gx4 = reinterpret_cast<const float4*>(x + (size_t)b0*CIN);
        float4* xs4 = reinterpret_cast<float4*>(xs);
        xs4[t]       = gx4[t];
        xs4[t + 256] = gx4[t + 256];
    }

    // ---- preload W1 column t (reused over 64 rows) ----
    float w1c[CIN];
    #pragma unroll
    for (int c = 0; c < CIN; c++) w1c[c] = W1[c*HID + t];
    const float b1t = b1[t];
    __syncthreads();

    // ---- z = tanh(x @ W1 + b1), thread t owns hidden unit t; 4 rows at a time ----
    for (int r = 0; r < TB; r += 4) {
        float a0 = b1t, a1 = b1t, a2 = b1t, a3 = b1t;
        const float4* x0 = reinterpret_cast<const float4*>(xs + (r+0)*CIN);
        const float4* x1 = reinterpret_cast<const float4*>(xs + (r+1)*CIN);
        const float4* x2 = reinterpret_cast<const float4*>(xs + (r+2)*CIN);
        const float4* x3 = reinterpret_cast<const float4*>(xs + (r+3)*CIN);
        #pragma unroll
        for (int c4 = 0; c4 < CIN/4; c4++) {
            float4 v0 = x0[c4], v1 = x1[c4], v2 = x2[c4], v3 = x3[c4];
            float w0 = w1c[c4*4+0], w1 = w1c[c4*4+1], w2 = w1c[c4*4+2], w3 = w1c[c4*4+3];
            a0 += v0.x*w0; a0 += v0.y*w1; a0 += v0.z*w2; a0 += v0.w*w3;
            a1 += v1.x*w0; a1 += v1.y*w1; a1 += v1.z*w2; a1 += v1.w*w3;
            a2 += v2.x*w0; a2 += v2.y*w1; a2 += v2.z*w2; a2 += v2.w*w3;
            a3 += v3.x*w0; a3 += v3.y*w1; a3 += v3.z*w2; a3 += v3.w*w3;
        }
        zs[r+0][t] = __float2bfloat16(tanhf(a0));
        zs[r+1][t] = __float2bfloat16(tanhf(a1));
        zs[r+2][t] = __float2bfloat16(tanhf(a2));
        zs[r+3][t] = __float2bfloat16(tanhf(a3));
    }
    __syncthreads();
    // ======== no barriers below this line: stores stream to kernel end ======

    // ---- MFMA setup ----
    const int w    = t >> 6;       // wave 0..3
    const int lane = t & 63;
    const int wm   = w >> 1;       // wave row 0..1  (32 rows each)
    const int wn   = w & 1;        // wave col 0..1  (32 cols each)
    const int lr   = lane & 15;    // fragment row/col
    const int lk   = lane >> 4;    // k-slice / row-group

    // per-lane diagonal unit pattern (diag position = lr)
    const int di = lr;
    f32x4 u0 = { di==0 ?1.f:0.f, di==1 ?1.f:0.f, di==2 ?1.f:0.f, di==3 ?1.f:0.f };
    f32x4 u1 = { di==4 ?1.f:0.f, di==5 ?1.f:0.f, di==6 ?1.f:0.f, di==7 ?1.f:0.f };
    f32x4 u2 = { di==8 ?1.f:0.f, di==9 ?1.f:0.f, di==10?1.f:0.f, di==11?1.f:0.f };
    f32x4 u3 = { di==12?1.f:0.f, di==13?1.f:0.f, di==14?1.f:0.f, di==15?1.f:0.f };

    // A-fragment base pointers (zs rows owned by this wave's m-tiles)
    const short8* A0 = reinterpret_cast<const short8*>(&zs[wm*32 +      lr][0]);
    const short8* A1 = reinterpret_cast<const short8*>(&zs[wm*32 + 16 + lr][0]);
    // 33 short8 per zs row
    #define ZROW 33

    // ---- 8 chunks of 64 cols: 0..3 sigma, 4..7 mu; B direct from global ----
    for (int chunk = 0; chunk < 8; chunk++) {
        const bool is_sig = (chunk < 4);
        const int c0 = (chunk & 3) * 64;
        const __hip_bfloat16* wbase =
            wsb + (is_sig ? WSIG_OFF : WMU_OFF) + (size_t)c0*256;
        // B rows for this wave: n = wn*32 + {0,16} + lr ; 32 short8 per row
        const short8* B0 = reinterpret_cast<const short8*>(wbase + (wn*32 +      lr)*256);
        const short8* B1 = reinterpret_cast<const short8*>(wbase + (wn*32 + 16 + lr)*256);

        f32x4 acc[2][2] = {};
        #pragma unroll
        for (int kk = 0; kk < 8; kk++) {
            const int fi = kk*4 + lk;           // short8 index: (kk*32+lk*8)/8
            short8 af0 = A0[kk*4 + lk + 0];     // zs strided by ZROW handled below
            short8 af1 = A1[kk*4 + lk + 0];
            short8 bf0 = B0[fi];
            short8 bf1 = B1[fi];
            acc[0][0] = __builtin_amdgcn_mfma_f32_16x16x32_bf16(af0, bf0, acc[0][0], 0,0,0);
            acc[0][1] = __builtin_amdgcn_mfma_f32_16x16x32_bf16(af0, bf1, acc[0][1], 0,0,0);
            acc[1][0] = __builtin_amdgcn_mfma_f32_16x16x32_bf16(af1, bf0, acc[1][0], 0,0,0);
            acc[1][1] = __builtin_amdgcn_mfma_f32_16x16x32_bf16(af1, bf1, acc[1][1], 0,0,0);
        }

        if (is_sig) {
            #pragma unroll
            for (int ni = 0; ni < 2; ni++) {
                const int c = c0 + wn*32 + ni*16 + lr;   // sigma-diag col, c%16 == lr
                const float bs = bsig[c];
                #pragma unroll
                for (int mi = 0; mi < 2; mi++) {
                    #pragma unroll
                    for (int j = 0; j < 4; j++) {
                        const int b = b0 + wm*32 + mi*16 + lk*4 + j;
                        const float sv = __expf(acc[mi][ni][j] + bs);
                        f32x4* dst = reinterpret_cast<f32x4*>(
                            out_sig + (size_t)b*4096 + (size_t)c*16);
                        __builtin_nontemporal_store(u0 * sv, dst + 0);
                        __builtin_nontemporal_store(u1 * sv, dst + 1);
                        __builtin_nontemporal_store(u2 * sv, dst + 2);
                        __builtin_nontemporal_store(u3 * sv, dst + 3);
                    }
                }
            }
        } else {
            #pragma unroll
            for (int ni = 0; ni < 2; ni++) {
                const int c = c0 + wn*32 + ni*16 + lr;   // mu col
                const float bm = bmu[c];
                #pragma unroll
                for (int mi = 0; mi < 2; mi++) {
                    #pragma unroll
                    for (int j = 0; j < 4; j++) {
                        const int b = b0 + wm*32 + mi*16 + lk*4 + j;
                        __builtin_nontemporal_store(acc[mi][ni][j] + bm,
                                                    &out_mu[(size_t)b*256 + c]);
                    }
                }
            }
        }
    }

    // ---- pi: 16 cols, each wave owns a 16-row m-tile; B from global ----
    {
        const short8* Ap = reinterpret_cast<const short8*>(&zs[w*16 + lr][0]);
        const short8* Bp = reinterpret_cast<const short8*>(wsb + WPI_OFF + lr*256);

        f32x4 pacc = {};
        #pragma unroll
        for (int kk = 0; kk < 8; kk++) {
            short8 af = Ap[kk*4 + lk];
            short8 bf = Bp[kk*4 + lk];
            pacc = __builtin_amdgcn_mfma_f32_16x16x32_bf16(af, bf, pacc, 0,0,0);
        }
        const float bp = bpi[lr];
        #pragma unroll
        for (int j = 0; j < 4; j++) {
            float v = pacc[j] + bp;
            float m = v;
            m = fmaxf(m, __shfl_xor(m, 1));
            m = fmaxf(m, __shfl_xor(m, 2));
            m = fmaxf(m, __shfl_xor(m, 4));
            m = fmaxf(m, __shfl_xor(m, 8));
            float e = __expf(v - m);
            float s = e;
            s += __shfl_xor(s, 1);
            s += __shfl_xor(s, 2);
            s += __shfl_xor(s, 4);
            s += __shfl_xor(s, 8);
            const int b = b0 + w*16 + lk*4 + j;
            out_pi[(size_t)b*16 + lr] = e / s;
        }
    }
}

extern "C" void kernel_launch(void* const* d_in, const int* in_sizes, int n_in,
                              void* d_out, int out_size, void* d_ws, size_t ws_size,
                              hipStream_t stream) {
    (void)in_sizes; (void)n_in; (void)out_size; (void)ws_size;
    const float* x    = (const float*)d_in[0];
    const float* W1   = (const float*)d_in[1];
    const float* b1   = (const float*)d_in[2];
    const float* Wpi  = (const float*)d_in[3];
    const float* bpi  = (const float*)d_in[4];
    const float* Wsig = (const float*)d_in[5];
    const float* bsig = (const float*)d_in[6];
    const float* Wmu  = (const float*)d_in[7];
    const float* bmu  = (const float*)d_in[8];
    float* out = (float*)d_out;
    __hip_bfloat16* wsb = (__hip_bfloat16*)d_ws;   // 270336 bytes used

    cvt_weights<<<528, 256, 0, stream>>>(Wpi, Wsig, Wmu, wsb);
    mdn_main<<<NB/TB, 256, 0, stream>>>(x, W1, b1, bpi, bsig, bmu, wsb, out);
}

// Round 3
// 248.168 us; speedup vs baseline: 7.8599x; 7.8599x over previous
//
#include <hip/hip_runtime.h>
#include <hip/hip_bf16.h>

// MDN: B=65536, COND=32, D=16, H=256, K=16
//  pi    = softmax(z @ Wpi + bpi)            [B,16]
//  sigma = diag_embed(exp(z @ Wsig + bsig))  [B,16,16,16]
//  mu    = z @ Wmu + bmu                     [B,16,16]
//  z = tanh(x @ W1 + b1)                     [B,256]
//
// Write-bound: 1.145 GB output => ~175 us floor at 6.5 TB/s.
// R2: every streaming store is LANE-CONTIGUOUS (64 lanes x 16B = 1KB/instr,
// the fillBuffer pattern) via a wave-private LDS bounce; no block barriers
// after the z-phase; nontemporal only on full-line coalesced stores.
// (R1 lesson: per-lane-owns-64B scatter = 64 lines/instr, and nt partial-line
// stores double WRITE_SIZE via L2-bypass.)

typedef __attribute__((ext_vector_type(8))) short short8;   // 8 bf16
typedef __attribute__((ext_vector_type(4))) float f32x4;

#define NB 65536
#define TB 64          // batch rows per block
#define HID 256
#define CIN 32

// ws layout (bf16): wpi_t [16][256] | wsig_t [256][256] | wmu_t [256][256]
#define WPI_OFF  0
#define WSIG_OFF (16*256)
#define WMU_OFF  (16*256 + 256*256)

__global__ __launch_bounds__(256) void cvt_weights(
    const float* __restrict__ Wpi, const float* __restrict__ Wsig,
    const float* __restrict__ Wmu, __hip_bfloat16* __restrict__ wsb)
{
    int r = blockIdx.x;      // 0..527 = output col -> transposed row
    int k = threadIdx.x;     // 0..255 = H index
    if (r < 16)
        wsb[WPI_OFF + r*256 + k] = __float2bfloat16(Wpi[k*16 + r]);
    else if (r < 272)
        wsb[WSIG_OFF + (r-16)*256 + k] = __float2bfloat16(Wsig[k*256 + (r-16)]);
    else
        wsb[WMU_OFF + (r-272)*256 + k] = __float2bfloat16(Wmu[k*256 + (r-272)]);
}

__global__ __launch_bounds__(256, 3) void mdn_main(
    const float* __restrict__ x, const float* __restrict__ W1,
    const float* __restrict__ b1, const float* __restrict__ bpi,
    const float* __restrict__ bsig, const float* __restrict__ bmu,
    const __hip_bfloat16* __restrict__ wsb,
    float* __restrict__ out)
{
    // LDS: zs 33792B + scratch 20480B = 54272B -> 3 blocks/CU (162816 <= 163840)
    __shared__ alignas(16) __hip_bfloat16 zs[TB][264];
    __shared__ alignas(16) float scratch[4][32][40];   // per-wave [32 rows][32 cols + pad]

    const int t  = threadIdx.x;
    const int b0 = blockIdx.x * TB;

    float* out_pi  = out;
    float* out_sig = out + (size_t)NB*16;
    float* out_mu  = out + (size_t)NB*16 + (size_t)NB*4096;

    // ---- load x tile [64][32] into scratch-as-xs (coalesced float4) ----
    float* xs = &scratch[0][0][0];   // 8KB, dead after z-phase
    {
        const float4* gx4 = reinterpret_cast<const float4*>(x + (size_t)b0*CIN);
        float4* xs4 = reinterpret_cast<float4*>(xs);
        xs4[t]       = gx4[t];
        xs4[t + 256] = gx4[t + 256];
    }

    // ---- preload W1 column t (reused over 64 rows) ----
    float w1c[CIN];
    #pragma unroll
    for (int c = 0; c < CIN; c++) w1c[c] = W1[c*HID + t];
    const float b1t = b1[t];
    __syncthreads();

    // ---- z = tanh(x @ W1 + b1), thread t owns hidden unit t ----
    for (int r = 0; r < TB; r += 4) {
        float a0 = b1t, a1 = b1t, a2 = b1t, a3 = b1t;
        const float4* x0 = reinterpret_cast<const float4*>(xs + (r+0)*CIN);
        const float4* x1 = reinterpret_cast<const float4*>(xs + (r+1)*CIN);
        const float4* x2 = reinterpret_cast<const float4*>(xs + (r+2)*CIN);
        const float4* x3 = reinterpret_cast<const float4*>(xs + (r+3)*CIN);
        #pragma unroll
        for (int c4 = 0; c4 < CIN/4; c4++) {
            float4 v0 = x0[c4], v1 = x1[c4], v2 = x2[c4], v3 = x3[c4];
            float w0 = w1c[c4*4+0], w1 = w1c[c4*4+1], w2 = w1c[c4*4+2], w3 = w1c[c4*4+3];
            a0 += v0.x*w0; a0 += v0.y*w1; a0 += v0.z*w2; a0 += v0.w*w3;
            a1 += v1.x*w0; a1 += v1.y*w1; a1 += v1.z*w2; a1 += v1.w*w3;
            a2 += v2.x*w0; a2 += v2.y*w1; a2 += v2.z*w2; a2 += v2.w*w3;
            a3 += v3.x*w0; a3 += v3.y*w1; a3 += v3.z*w2; a3 += v3.w*w3;
        }
        // fast tanh: 1 - 2/(e^{2a}+1)  (correct limits at +-inf)
        zs[r+0][t] = __float2bfloat16(1.0f - 2.0f/(__expf(2.0f*a0)+1.0f));
        zs[r+1][t] = __float2bfloat16(1.0f - 2.0f/(__expf(2.0f*a1)+1.0f));
        zs[r+2][t] = __float2bfloat16(1.0f - 2.0f/(__expf(2.0f*a2)+1.0f));
        zs[r+3][t] = __float2bfloat16(1.0f - 2.0f/(__expf(2.0f*a3)+1.0f));
    }
    __syncthreads();
    // ======== no block barriers below this line ========

    // ---- MFMA setup ----
    const int w    = t >> 6;       // wave 0..3
    const int lane = t & 63;
    const int wm   = w >> 1;       // wave row 0..1  (32 batch rows each)
    const int wn   = w & 1;        // wave col 0..1  (32 out cols each)
    const int lr   = lane & 15;    // fragment row/col
    const int lk   = lane >> 4;    // k-slice / row-group

    const short8* A0 = reinterpret_cast<const short8*>(&zs[wm*32 +      lr][0]);
    const short8* A1 = reinterpret_cast<const short8*>(&zs[wm*32 + 16 + lr][0]);
    float* scr = &scratch[w][0][0];          // wave-private [32][40]

    // sigma fill-phase lane roles
    const int cidx = lane >> 2;              // 0..15 : col within 16-col block
    const int q    = lane & 3;               // quarter (4 floats) within 64B row
    const int epos = cidx - 4*q;             // nonzero element idx if in [0,4)
    // mu fill-phase lane roles
    const int mrr = lane >> 3;               // 0..7
    const int mcc = (lane & 7) * 4;          // 0,4,..,28

    f32x4* const sig4 = reinterpret_cast<f32x4*>(out_sig);
    f32x4* const mu4  = reinterpret_cast<f32x4*>(out_mu);

    // ---- 8 chunks of 64 cols: 0..3 sigma, 4..7 mu; B direct from global/L2 ----
    for (int chunk = 0; chunk < 8; chunk++) {
        const bool is_sig = (chunk < 4);
        const int c0 = (chunk & 3) * 64;
        const __hip_bfloat16* wbase =
            wsb + (is_sig ? WSIG_OFF : WMU_OFF) + (size_t)c0*256;
        const short8* B0 = reinterpret_cast<const short8*>(wbase + (wn*32 +      lr)*256);
        const short8* B1 = reinterpret_cast<const short8*>(wbase + (wn*32 + 16 + lr)*256);

        f32x4 acc[2][2] = {};
        #pragma unroll
        for (int kk = 0; kk < 8; kk++) {
            const int fi = kk*4 + lk;
            short8 af0 = A0[fi];
            short8 af1 = A1[fi];
            short8 bf0 = B0[fi];
            short8 bf1 = B1[fi];
            acc[0][0] = __builtin_amdgcn_mfma_f32_16x16x32_bf16(af0, bf0, acc[0][0], 0,0,0);
            acc[0][1] = __builtin_amdgcn_mfma_f32_16x16x32_bf16(af0, bf1, acc[0][1], 0,0,0);
            acc[1][0] = __builtin_amdgcn_mfma_f32_16x16x32_bf16(af1, bf0, acc[1][0], 0,0,0);
            acc[1][1] = __builtin_amdgcn_mfma_f32_16x16x32_bf16(af1, bf1, acc[1][1], 0,0,0);
        }

        // wait for any pending scratch reads from previous chunk (WAR)
        asm volatile("s_waitcnt lgkmcnt(0)" ::: "memory");

        // ---- stage this wave's 32x32 value tile into private scratch ----
        #pragma unroll
        for (int ni = 0; ni < 2; ni++) {
            const int c = c0 + wn*32 + ni*16 + lr;
            const float bias = is_sig ? bsig[c] : bmu[c];
            #pragma unroll
            for (int mi = 0; mi < 2; mi++) {
                #pragma unroll
                for (int j = 0; j < 4; j++) {
                    const int row = mi*16 + lk*4 + j;
                    const int col = ni*16 + lr;
                    float v = acc[mi][ni][j] + bias;
                    scr[row*40 + col] = is_sig ? __expf(v) : v;
                }
            }
        }
        asm volatile("s_waitcnt lgkmcnt(0)" ::: "memory");

        // ---- coalesced fill phase (wave-local, no barrier) ----
        if (is_sig) {
            // per (r, cb): 64 lanes x 16B = 1KB contiguous
            #pragma unroll 4
            for (int r = 0; r < 32; r++) {
                size_t base = (size_t)(b0 + wm*32 + r) * 1024
                            + (size_t)(c0 + wn*32) * 4 + lane;
                #pragma unroll
                for (int cb = 0; cb < 2; cb++) {
                    float val = scr[r*40 + cb*16 + cidx];
                    f32x4 v;
                    v[0] = (epos == 0) ? val : 0.0f;
                    v[1] = (epos == 1) ? val : 0.0f;
                    v[2] = (epos == 2) ? val : 0.0f;
                    v[3] = (epos == 3) ? val : 0.0f;
                    __builtin_nontemporal_store(v, sig4 + base + cb*64);
                }
            }
        } else {
            // per it: 8 rows x 128B segments, all lines full
            #pragma unroll
            for (int it = 0; it < 4; it++) {
                const int r = it*8 + mrr;
                f32x4 v = *reinterpret_cast<const f32x4*>(&scr[r*40 + mcc]);
                size_t base = (size_t)(b0 + wm*32 + r) * 64
                            + (size_t)(c0 + wn*32) / 4 + (lane & 7);
                __builtin_nontemporal_store(v, mu4 + base);
            }
        }
    }

    // ---- pi: 16 cols, each wave owns a 16-row m-tile; B from global ----
    {
        const short8* Ap = reinterpret_cast<const short8*>(&zs[w*16 + lr][0]);
        const short8* Bp = reinterpret_cast<const short8*>(wsb + WPI_OFF + lr*256);

        f32x4 pacc = {};
        #pragma unroll
        for (int kk = 0; kk < 8; kk++) {
            short8 af = Ap[kk*4 + lk];
            short8 bf = Bp[kk*4 + lk];
            pacc = __builtin_amdgcn_mfma_f32_16x16x32_bf16(af, bf, pacc, 0,0,0);
        }
        const float bp = bpi[lr];
        #pragma unroll
        for (int j = 0; j < 4; j++) {
            float v = pacc[j] + bp;
            float m = v;
            m = fmaxf(m, __shfl_xor(m, 1));
            m = fmaxf(m, __shfl_xor(m, 2));
            m = fmaxf(m, __shfl_xor(m, 4));
            m = fmaxf(m, __shfl_xor(m, 8));
            float e = __expf(v - m);
            float s = e;
            s += __shfl_xor(s, 1);
            s += __shfl_xor(s, 2);
            s += __shfl_xor(s, 4);
            s += __shfl_xor(s, 8);
            const int b = b0 + w*16 + lk*4 + j;
            out_pi[(size_t)b*16 + lr] = e / s;
        }
    }
}

extern "C" void kernel_launch(void* const* d_in, const int* in_sizes, int n_in,
                              void* d_out, int out_size, void* d_ws, size_t ws_size,
                              hipStream_t stream) {
    (void)in_sizes; (void)n_in; (void)out_size; (void)ws_size;
    const float* x    = (const float*)d_in[0];
    const float* W1   = (const float*)d_in[1];
    const float* b1   = (const float*)d_in[2];
    const float* Wpi  = (const float*)d_in[3];
    const float* bpi  = (const float*)d_in[4];
    const float* Wsig = (const float*)d_in[5];
    const float* bsig = (const float*)d_in[6];
    const float* Wmu  = (const float*)d_in[7];
    const float* bmu  = (const float*)d_in[8];
    float* out = (float*)d_out;
    __hip_bfloat16* wsb = (__hip_bfloat16*)d_ws;   // 270336 bytes used

    cvt_weights<<<528, 256, 0, stream>>>(Wpi, Wsig, Wmu, wsb);
    mdn_main<<<NB/TB, 256, 0, stream>>>(x, W1, b1, bpi, bsig, bmu, wsb, out);
}